// Round 3
// baseline (172.151 us; speedup 1.0000x reference)
//
#include <hip/hip_runtime.h>

// Problem constants (static in the reference: D1=D2=32, ADD1=ADD2=16, BATCH=8)
constexpr int FOCK_DIM = 4656;          // m*(m+1)/2 with m=96, 2 photons
constexpr int N        = 1024;          // D1*D2
constexpr int ROW_VEC  = FOCK_DIM / 4;  // 1164 float4 per output row
constexpr int B        = 8;             // batch
constexpr int BCHUNK   = 4;             // batches staged in LDS at once (16 KB)

typedef float f32x4 __attribute__((ext_vector_type(4)));
typedef int   i32x4 __attribute__((ext_vector_type(4)));

// --- build inverse map: inv[f] = i such that fock_idx[i]==f, else -1 ---
__global__ __launch_bounds__(256) void build_inv_kernel(
    const int* __restrict__ fock_idx, int* __restrict__ inv) {
    const int f = blockIdx.x * 256 + threadIdx.x;
    if (f >= FOCK_DIM) return;
    int r = -1;
    for (int i = 0; i < N; ++i) {
        if (fock_idx[i] == f) r = i;
    }
    inv[f] = r;
}

// --- main kernel: one block per Fock row r, covering ALL 8 batches ---
// out[b, r, c] = (inv[r]>=0 && inv[c]>=0) ? in[b, inv[r], inv[c]] : 0
__global__ __launch_bounds__(256) void scatter_rows_kernel(
    const float* __restrict__ in,
    const int*   __restrict__ inv,
    float*       __restrict__ out) {

    const int r    = blockIdx.x;
    const int tid  = threadIdx.x;
    const int invr = inv[r];

    if (invr < 0) {
        // dead row in all 8 batches: pure zero stream, flattened over (b, c4)
        const f32x4 z = {0.f, 0.f, 0.f, 0.f};
        const int total4 = B * ROW_VEC;  // 9312
        for (int t = tid; t < total4; t += 256) {
            const int b  = t / ROW_VEC;          // const-div -> mul_hi
            const int c4 = t - b * ROW_VEC;
            f32x4* orow = reinterpret_cast<f32x4*>(out + ((size_t)b * FOCK_DIM + r) * FOCK_DIM);
            __builtin_nontemporal_store(z, orow + c4);
        }
        return;
    }

    // live row: stage BCHUNK input rows in LDS, gather by inv[c], x2 chunks
    __shared__ float rows[BCHUNK][N];
    const f32x4* __restrict__ in4  = reinterpret_cast<const f32x4*>(in);
    const i32x4* __restrict__ inv4 = reinterpret_cast<const i32x4*>(inv);

    for (int chunk = 0; chunk < B / BCHUNK; ++chunk) {
        const int b0 = chunk * BCHUNK;

        // stage BCHUNK rows (4 KB each), float4-vectorized, coalesced
        for (int t = tid; t < BCHUNK * (N / 4); t += 256) {
            const int bb = t >> 8;       // N/4 == 256 float4 per row
            const int c  = t & 255;
            f32x4 v = in4[((size_t)(b0 + bb) * N + (size_t)invr) * (N / 4) + c];
            reinterpret_cast<f32x4*>(rows[bb])[c] = v;
        }
        __syncthreads();

        // gather + store: one inv4 load feeds BCHUNK output rows
        for (int c4 = tid; c4 < ROW_VEC; c4 += 256) {
            const i32x4 iv = inv4[c4];
            #pragma unroll
            for (int bb = 0; bb < BCHUNK; ++bb) {
                f32x4 v;
                v.x = (iv.x >= 0) ? rows[bb][iv.x] : 0.f;
                v.y = (iv.y >= 0) ? rows[bb][iv.y] : 0.f;
                v.z = (iv.z >= 0) ? rows[bb][iv.z] : 0.f;
                v.w = (iv.w >= 0) ? rows[bb][iv.w] : 0.f;
                f32x4* orow = reinterpret_cast<f32x4*>(
                    out + ((size_t)(b0 + bb) * FOCK_DIM + r) * FOCK_DIM);
                __builtin_nontemporal_store(v, orow + c4);
            }
        }
        if (chunk == 0) __syncthreads();  // protect rows[] before re-staging
    }
}

extern "C" void kernel_launch(void* const* d_in, const int* in_sizes, int n_in,
                              void* d_out, int out_size, void* d_ws, size_t ws_size,
                              hipStream_t stream) {
    const float* in       = (const float*)d_in[0];   // [B, 1024, 1024] fp32
    const int*   fock_idx = (const int*)d_in[1];     // [1024] int32
    float*       out      = (float*)d_out;           // [B, 4656, 4656] fp32
    int*         inv      = (int*)d_ws;              // 4656 int32 scratch

    build_inv_kernel<<<(FOCK_DIM + 255) / 256, 256, 0, stream>>>(fock_idx, inv);
    scatter_rows_kernel<<<FOCK_DIM, 256, 0, stream>>>(in, inv, out);
}

// Round 4
// 153.415 us; speedup vs baseline: 1.1221x; 1.1221x over previous
//
#include <hip/hip_runtime.h>

// Problem constants (static in the reference: D1=D2=32, ADD1=ADD2=16, BATCH=8)
constexpr int FOCK_DIM = 4656;          // m*(m+1)/2 with m=96, 2 photons
constexpr int N        = 1024;          // D1*D2
constexpr int ROW_VEC  = FOCK_DIM / 4;  // 1164 float4 per output row

typedef float f32x4 __attribute__((ext_vector_type(4)));
typedef int   i32x4 __attribute__((ext_vector_type(4)));

// --- build inverse map: inv[f] = i such that fock_idx[i]==f, else -1 ---
__global__ __launch_bounds__(256) void init_inv_kernel(int* __restrict__ inv) {
    int i = blockIdx.x * 256 + threadIdx.x;
    if (i < FOCK_DIM) inv[i] = -1;
}

__global__ __launch_bounds__(256) void fill_inv_kernel(const int* __restrict__ fock_idx,
                                                       int* __restrict__ inv) {
    int i = blockIdx.x * 256 + threadIdx.x;
    if (i < N) inv[fock_idx[i]] = i;
}

// --- main kernel: one block per output row (b, r), no LDS, no syncthreads ---
// out[b, r, c] = (inv[r]>=0 && inv[c]>=0) ? in[b, inv[r], inv[c]] : 0
// Injective fock_idx => each input element is used exactly once per row:
// no reuse, so gather directly through L1 (4 KB row window) instead of LDS.
__global__ __launch_bounds__(256) void scatter_rows_kernel(
    const float* __restrict__ in,
    const int*   __restrict__ inv,
    float*       __restrict__ out) {

    const int br  = blockIdx.x;          // b * FOCK_DIM + r
    const int b   = br / FOCK_DIM;       // magic-mul, once per block
    const int r   = br - b * FOCK_DIM;
    const int x   = inv[r];              // wave-uniform

    f32x4* __restrict__ orow = reinterpret_cast<f32x4*>(out + (size_t)br * FOCK_DIM);

    if (x < 0) {
        // dead row: pure zero stream, plain (cached) stores
        const f32x4 z = {0.f, 0.f, 0.f, 0.f};
        for (int c4 = threadIdx.x; c4 < ROW_VEC; c4 += 256) {
            orow[c4] = z;
        }
        return;
    }

    // live row: direct gather from the 4 KB input row via L1
    const float* __restrict__ irow = in + ((size_t)b * N + (size_t)x) * N;
    const i32x4* __restrict__ inv4 = reinterpret_cast<const i32x4*>(inv);
    for (int c4 = threadIdx.x; c4 < ROW_VEC; c4 += 256) {
        const i32x4 iv = inv4[c4];
        f32x4 v;
        v.x = (iv.x >= 0) ? irow[iv.x] : 0.f;
        v.y = (iv.y >= 0) ? irow[iv.y] : 0.f;
        v.z = (iv.z >= 0) ? irow[iv.z] : 0.f;
        v.w = (iv.w >= 0) ? irow[iv.w] : 0.f;
        orow[c4] = v;
    }
}

extern "C" void kernel_launch(void* const* d_in, const int* in_sizes, int n_in,
                              void* d_out, int out_size, void* d_ws, size_t ws_size,
                              hipStream_t stream) {
    const float* in       = (const float*)d_in[0];   // [B, 1024, 1024] fp32
    const int*   fock_idx = (const int*)d_in[1];     // [1024] int32
    float*       out      = (float*)d_out;           // [B, 4656, 4656] fp32
    int*         inv      = (int*)d_ws;              // 4656 int32 scratch

    const int B = in_sizes[0] / (N * N);             // 8

    init_inv_kernel<<<(FOCK_DIM + 255) / 256, 256, 0, stream>>>(inv);
    fill_inv_kernel<<<(N + 255) / 256, 256, 0, stream>>>(fock_idx, inv);
    scatter_rows_kernel<<<B * FOCK_DIM, 256, 0, stream>>>(in, inv, out);
}